// Round 1
// baseline (232.941 us; speedup 1.0000x reference)
//
#include <hip/hip_runtime.h>
#include <hip/hip_bf16.h>

#define DIM 32

// Kernel 1: out[i] = x[i] @ W2^T + b2 ; y[i] = x[i] @ W1^T
// Block = 256 threads = 8 rows x 32 cols.
__global__ __launch_bounds__(256) void fused_lin_kernel(
    const float* __restrict__ x,
    const float* __restrict__ W1,
    const float* __restrict__ W2,
    const float* __restrict__ b2,
    float* __restrict__ out,
    float* __restrict__ y,
    int n_nodes)
{
    __shared__ float W1s[DIM][DIM];  // W1s[k][c] = W1[c][k]  (transposed)
    __shared__ float W2s[DIM][DIM];  // W2s[k][c] = W2[c][k]
    __shared__ float b2s[DIM];
    __shared__ float xs[8][DIM];

    const int t = threadIdx.x;

    // Stage weights transposed: global index i = c*32 + k  ->  Ws[k][c]
    #pragma unroll
    for (int i = t; i < DIM * DIM; i += 256) {
        int c = i >> 5;
        int k = i & 31;
        W1s[k][c] = W1[i];
        W2s[k][c] = W2[i];
    }
    if (t < DIM) b2s[t] = b2[t];

    const int r = t >> 5;   // row within block tile (0..7)
    const int c = t & 31;   // output column (0..31)
    const int row = blockIdx.x * 8 + r;

    // Coalesced load of 8 rows of x into LDS
    if (row < n_nodes) {
        xs[r][c] = x[(long)row * DIM + c];
    }
    __syncthreads();

    if (row >= n_nodes) return;

    float a2 = b2s[c];
    float a1 = 0.0f;
    #pragma unroll
    for (int k = 0; k < DIM; ++k) {
        float xv = xs[r][k];             // broadcast within wave
        a2 += xv * W2s[k][c];            // conflict-free (bank = c)
        a1 += xv * W1s[k][c];
    }
    out[(long)row * DIM + c] = a2;
    y[(long)row * DIM + c]   = a1;
}

// Kernel 2: for each edge e: out[dst[e]][:] += y[src[e]][:]
// One thread per (edge, d) element: lanes d=0..31 of an edge hit a
// contiguous 128B segment -> one coalesced atomic instruction per edge pair.
__global__ __launch_bounds__(256) void edge_scatter_kernel(
    const int* __restrict__ src,
    const int* __restrict__ dst,
    const float* __restrict__ y,
    float* __restrict__ out,
    long total)  // n_edges * 32
{
    long gid = (long)blockIdx.x * 256 + threadIdx.x;
    if (gid >= total) return;
    int e = (int)(gid >> 5);
    int d = (int)(gid & 31);
    int s = src[e];
    int t = dst[e];
    float v = y[(long)s * DIM + d];
    atomicAdd(&out[(long)t * DIM + d], v);
}

extern "C" void kernel_launch(void* const* d_in, const int* in_sizes, int n_in,
                              void* d_out, int out_size, void* d_ws, size_t ws_size,
                              hipStream_t stream) {
    const float* x  = (const float*)d_in[0];
    const float* W1 = (const float*)d_in[1];
    const float* W2 = (const float*)d_in[2];
    const float* b2 = (const float*)d_in[3];
    const int*   ei = (const int*)d_in[4];   // [2, E] int32 (harness converts int64 -> int32)

    const int n_nodes = in_sizes[0] / DIM;       // 100000
    const int n_edges = in_sizes[4] / 2;         // 1,600,000
    const int* src = ei;
    const int* dst = ei + n_edges;

    float* out = (float*)d_out;
    float* y   = (float*)d_ws;                   // n_nodes * 32 floats = 12.8 MB

    // Kernel 1: out = x@W2^T + b2 ; y = x@W1^T
    {
        int blocks = (n_nodes + 7) / 8;
        fused_lin_kernel<<<blocks, 256, 0, stream>>>(x, W1, W2, b2, out, y, n_nodes);
    }

    // Kernel 2: scatter-add y[src] into out[dst]
    {
        long total = (long)n_edges * DIM;
        int blocks = (int)((total + 255) / 256);
        edge_scatter_kernel<<<blocks, 256, 0, stream>>>(src, dst, y, out, total);
    }
}